// Round 6
// baseline (47.036 us; speedup 1.0000x reference)
//
#include <hip/hip_runtime.h>

// Problem constants
#define B_IMG 8
#define C_IN  16
#define COUT  64
#define H0    36
#define H1    6
#define NB    6
// OH=OW=16; 2048 pixel-rows (8 img x 256); output [8][64][16][16]
// d_ws: h0 buffer [64][36][2048] floats = 18.9 MB

typedef float f32x2 __attribute__((ext_vector_type(2)));

__device__ __forceinline__ float sigf(float v) { return 1.0f / (1.0f + __expf(-v)); }

// 6-bit multilinear interp, delta-form table in registers.
// g[0] contracts the MSB ... g[5] the LSB (matches reference einsum order).
__device__ __forceinline__ float lut_contract_reg(const float4 lo4[8], const float4 dd4[8],
                                                  const float g[NB]) {
    f32x2 v[16];
    const float g0 = g[0];
#pragma unroll
    for (int q = 0; q < 8; ++q) {
        v[2*q+0] = (f32x2){lo4[q].x, lo4[q].y} + (f32x2){dd4[q].x, dd4[q].y} * g0;
        v[2*q+1] = (f32x2){lo4[q].z, lo4[q].w} + (f32x2){dd4[q].z, dd4[q].w} * g0;
    }
#pragma unroll
    for (int i = 1; i < 5; ++i) {
        const int vh = 16 >> i;
        const float gi = g[i];
#pragma unroll
        for (int r = 0; r < vh; ++r)
            v[r] += (v[r + vh] - v[r]) * gi;
    }
    return v[0].x + (v[0].y - v[0].x) * g[5];
}

// Load a raw 64-entry table (global, wave-uniform address), sigmoid it,
// and build delta form in VGPRs: lo[k]=sig(w[k]), dd[k]=sig(w[k+32])-lo[k].
__device__ __forceinline__ void load_sig_tbl(const float* __restrict__ tb,
                                             float4 lo4[8], float4 dd4[8]) {
    const float4* tp = (const float4*)tb;
#pragma unroll
    for (int q = 0; q < 8; ++q) {
        float4 a = tp[q], b = tp[q + 8];
        float4 l, d;
        l.x = sigf(a.x); l.y = sigf(a.y); l.z = sigf(a.z); l.w = sigf(a.w);
        d.x = sigf(b.x) - l.x; d.y = sigf(b.y) - l.y;
        d.z = sigf(b.z) - l.z; d.w = sigf(b.w) - l.w;
        lo4[q] = l; dd4[q] = d;
    }
}

// Layer 0: block = (node n, channel t). Self-prunes unused nodes, keeps its
// table in VGPRs, streams all 2048 pixels (8 chunks per wave).
__global__ __launch_bounds__(256) void lut0_kernel(
    const float* __restrict__ x,
    const int*   __restrict__ idx0,
    const float* __restrict__ table0,
    const int*   __restrict__ idx1,
    float*       __restrict__ h0)       // [64][36][2048]
{
    const int t = blockIdx.x & 63;
    const int n = blockIdx.x >> 6;

    // prune: node n used by any idx1[t][*][*]?
    const int* i1 = idx1 + t * (H1 * NB);
    bool used = false;
#pragma unroll
    for (int j = 0; j < H1 * NB; ++j) used |= (i1[j] == n);
    if (!used) return;

    // decode this node's 6 gather indices (wave-uniform -> SGPRs)
    const int* i0 = idx0 + ((size_t)t * H0 + n) * NB;
    int off[NB], kh[NB], kw[NB];
#pragma unroll
    for (int i = 0; i < NB; ++i) {
        int raw = i0[i];
        int c = raw / 25, rem = raw - c * 25;
        kh[i] = rem / 5; kw[i] = rem - kh[i] * 5;
        off[i] = c * 1024 + (kh[i] - 2) * 32 + (kw[i] - 2);
    }

    float4 lo4[8], dd4[8];
    load_sig_tbl(table0 + ((size_t)t * H0 + n) * 64, lo4, dd4);

    const int w = threadIdx.x >> 6, lane = threadIdx.x & 63;
    float* h0p = h0 + ((size_t)t * H0 + n) * 2048;

    for (int it = 0; it < 8; ++it) {
        const int px  = ((w << 3) + it) * 64 + lane;   // wave w owns px [512w, 512w+512)
        const int img = px >> 8, p8 = px & 255;
        const int oh  = p8 >> 4, ow = p8 & 15;
        const int base = img * 16384 + oh * 64 + ow * 2;   // oh2*32 + ow2
        const int hm = 0x1F ^ ((oh == 0) ? 0x03 : 0) ^ ((oh == 15) ? 0x10 : 0);
        const int wm = 0x1F ^ ((ow == 0) ? 0x03 : 0) ^ ((ow == 15) ? 0x10 : 0);
        float g[NB];
#pragma unroll
        for (int i = 0; i < NB; ++i) {
            const bool ok = (((hm >> kh[i]) & (wm >> kw[i])) & 1) != 0;
            const float v = x[ok ? (base + off[i]) : 0];
            g[i] = ok ? v : 0.0f;
        }
        h0p[px] = lut_contract_reg(lo4, dd4, g);
    }
}

// Layers 1+2: block = (channel t, 512-px group). Waves 0..5 own one L1 node
// each (table in VGPRs, 8 chunks); h1 in LDS; all 8 waves do one L2 chunk.
__global__ __launch_bounds__(512) void lut12_kernel(
    const float* __restrict__ h0,
    const int*   __restrict__ idx1,
    const float* __restrict__ table1,
    const int*   __restrict__ idx2,
    const float* __restrict__ table2,
    float*       __restrict__ out)
{
    __shared__ float h1s[H1 * 512];
    const int t  = blockIdx.x >> 2;
    const int pg = blockIdx.x & 3;
    const int w  = threadIdx.x >> 6, lane = threadIdx.x & 63;
    const float* h0T = h0 + (size_t)t * H0 * 2048 + pg * 512;

    if (w < H1) {
        float4 lo4[8], dd4[8];
        load_sig_tbl(table1 + ((size_t)t * H1 + w) * 64, lo4, dd4);
        const int* i1 = idx1 + ((size_t)t * H1 + w) * NB;
        const int s0 = i1[0], s1 = i1[1], s2 = i1[2];
        const int s3 = i1[3], s4 = i1[4], s5 = i1[5];
#pragma unroll
        for (int c = 0; c < 8; ++c) {
            const int px = (c << 6) + lane;
            float g[NB];
            g[0] = h0T[s0 * 2048 + px]; g[1] = h0T[s1 * 2048 + px];
            g[2] = h0T[s2 * 2048 + px]; g[3] = h0T[s3 * 2048 + px];
            g[4] = h0T[s4 * 2048 + px]; g[5] = h0T[s5 * 2048 + px];
            h1s[w * 512 + px] = lut_contract_reg(lo4, dd4, g);
        }
    }
    __syncthreads();

    {
        float4 lo4[8], dd4[8];
        load_sig_tbl(table2 + (size_t)t * 64, lo4, dd4);
        const int* i2 = idx2 + (size_t)t * NB;
        const int px = (w << 6) + lane;                 // chunk w of this 512-px group
        float g[NB];
#pragma unroll
        for (int i = 0; i < NB; ++i) g[i] = h1s[i2[i] * 512 + px];
        const float r = lut_contract_reg(lo4, dd4, g);
        const int gpx = (pg << 9) + px;
        const int img = gpx >> 8, p8 = gpx & 255;
        out[((size_t)img * COUT + t) * 256 + p8] = r;
    }
}

extern "C" void kernel_launch(void* const* d_in, const int* in_sizes, int n_in,
                              void* d_out, int out_size, void* d_ws, size_t ws_size,
                              hipStream_t stream) {
    const float* x      = (const float*)d_in[0];
    const int*   idx0   = (const int*)  d_in[1];
    const float* table0 = (const float*)d_in[2];
    const int*   idx1   = (const int*)  d_in[3];
    const float* table1 = (const float*)d_in[4];
    const int*   idx2   = (const int*)  d_in[5];
    const float* table2 = (const float*)d_in[6];
    float* out = (float*)d_out;
    float* h0  = (float*)d_ws;          // [64][36][2048]

    lut0_kernel <<<H0 * COUT, 256, 0, stream>>>(x, idx0, table0, idx1, h0);
    lut12_kernel<<<COUT * 4,  512, 0, stream>>>(h0, idx1, table1, idx2, table2, out);
}

// Round 7
// 37.960 us; speedup vs baseline: 1.2391x; 1.2391x over previous
//
#include <hip/hip_runtime.h>

// Problem constants
#define B_IMG 8
#define C_IN  16
#define COUT  64
#define H0    36
#define H1    6
#define NB    6
#define NNODE 43
// OH=OW=16; 2048 pixel-rows (8 img x 256); output [8][64][16][16]

// d_ws layout (float indices unless noted):
//   xp   [0 .. XPN)            padded x: [8][16][36][36], halo=2 (zero border)
//   tbl  [TBL_OFF ..)          per-(t,node) sigmoid'd delta tables: lo[32]|dd[32]
//   meta [META_OFF_I ints ..)  per-(t,L0-node): 6 gather offsets into xp (stride 8)
//   ch   [CH_OFF_I ints ..)    per-t: [0]=nU, [1..36]=usedList, [37..72]=idx1->slot
#define XPN        (B_IMG*C_IN*36*36)        // 165888
#define TBL_OFF    XPN
#define TBL_SZ     (COUT*NNODE*64)           // 176128
#define META_OFF_I (TBL_OFF + TBL_SZ)
#define META_SZ    (COUT*H0*8)               // 18432 ints
#define CH_OFF_I   (META_OFF_I + META_SZ)
#define CH_STRIDE  80

typedef float f32x2 __attribute__((ext_vector_type(2)));

__device__ __forceinline__ float sigf(float v) { return 1.0f / (1.0f + __expf(-v)); }

// 6-bit multilinear interp, delta-form table in registers.
// g[0] contracts the MSB ... g[5] the LSB (matches reference einsum order).
__device__ __forceinline__ float lut_contract_reg(const float4 lo4[8], const float4 dd4[8],
                                                  const float g[NB]) {
    f32x2 v[16];
    const float g0 = g[0];
#pragma unroll
    for (int q = 0; q < 8; ++q) {
        v[2*q+0] = (f32x2){lo4[q].x, lo4[q].y} + (f32x2){dd4[q].x, dd4[q].y} * g0;
        v[2*q+1] = (f32x2){lo4[q].z, lo4[q].w} + (f32x2){dd4[q].z, dd4[q].w} * g0;
    }
#pragma unroll
    for (int i = 1; i < 5; ++i) {
        const int vh = 16 >> i;
        const float gi = g[i];
#pragma unroll
        for (int r = 0; r < vh; ++r)
            v[r] += (v[r + vh] - v[r]) * gi;
    }
    return v[0].x + (v[0].y - v[0].x) * g[5];
}

__device__ __forceinline__ void load_tbl(const float* __restrict__ tb,
                                         float4 lo4[8], float4 dd4[8]) {
    const float4* t4 = (const float4*)tb;
#pragma unroll
    for (int q = 0; q < 8; ++q) { lo4[q] = t4[q]; dd4[q] = t4[q + 8]; }
}

__global__ __launch_bounds__(256) void setup_kernel(
    const float* __restrict__ x,
    const float* __restrict__ t0,
    const float* __restrict__ t1,
    const float* __restrict__ t2,
    const int*   __restrict__ idx0,
    const int*   __restrict__ idx1,
    float*       __restrict__ ws)
{
    int id = blockIdx.x * 256 + threadIdx.x;
    int* wsI = (int*)ws;
    if (id < XPN) {                               // pad x -> xp [8][16][36][36]
        int img = id / 20736, r = id % 20736;
        int c   = r / 1296,  r2 = r % 1296;
        int ih  = r2 / 36,   iw = r2 % 36;
        int ihs = ih - 2,    iws = iw - 2;
        bool ok = ((unsigned)ihs < 32u) & ((unsigned)iws < 32u);
        ws[id] = ok ? x[((img*C_IN + c)*32 + ihs)*32 + iws] : 0.0f;
        return;
    }
    id -= XPN;
    if (id < COUT*NNODE*32) {                     // sigmoid'd delta tables
        int k = id & 31, tn = id >> 5;
        int node = tn % NNODE, t = tn / NNODE;
        const float* src = (node < H0)    ? t0 + ((size_t)t*H0 + node)*64
                         : (node < H0+H1) ? t1 + ((size_t)t*H1 + node - H0)*64
                                          : t2 + (size_t)t*64;
        float lo = sigf(src[k]);
        float hi = sigf(src[k + 32]);
        ws[TBL_OFF + tn*64 + k]      = lo;
        ws[TBL_OFF + tn*64 + 32 + k] = hi - lo;
        return;
    }
    id -= COUT*NNODE*32;
    if (id < COUT*H0*NB) {                        // gather offsets into xp
        int i = id % NB, nn = (id/NB) % H0, t = id/(NB*H0);
        int raw = idx0[(size_t)t*(H0*NB) + nn*NB + i];
        int c = raw / 25, rem = raw - c*25, kh = rem / 5, kw = rem - kh*5;
        wsI[META_OFF_I + (t*H0 + nn)*8 + i] = c*1296 + kh*36 + kw;
        return;
    }
    id -= COUT*H0*NB;
    if (id < COUT) {                              // prune + remap per channel
        int t = id;
        int* ch = wsI + CH_OFF_I + t*CH_STRIDE;
        unsigned long long mask = 0;
        for (int j = 0; j < H1*NB; ++j) mask |= 1ull << idx1[(size_t)t*(H1*NB) + j];
        int cnt = 0;
        for (int n = 0; n < H0; ++n) if ((mask >> n) & 1ull) ch[1 + cnt++] = n;
        ch[0] = cnt;
        for (int j = 0; j < H1*NB; ++j) {
            int raw = idx1[(size_t)t*(H1*NB) + j];
            ch[1 + H0 + j] = __popcll(mask & ((1ull << raw) - 1ull));
        }
    }
}

// Fused layers 0+1+2. Block = (channel t, image img, 128-px half):
// 256 threads = 4 waves. h0/h1 in LDS (21 KB); tables in VGPRs per (wave,node).
// NOTE: no min-waves in launch_bounds — forcing occupancy caps VGPR at 128 and
// spills the register-resident tables to scratch (R3 evidence: VGPR_Count=32).
__global__ __launch_bounds__(256) void lutfused_kernel(
    const float* __restrict__ xp,
    const float* __restrict__ tbl,
    const int*   __restrict__ meta,
    const int*   __restrict__ ch,
    const int*   __restrict__ idx2,
    float*       __restrict__ out)
{
    __shared__ float h0s[H0*128];   // [slot][px] — bank = px, conflict-free
    __shared__ float h1s[H1*128];

    const int tid  = threadIdx.x;
    const int w    = tid >> 6;
    const int lane = tid & 63;
    const int t    = blockIdx.x & 63;
    const int rest = blockIdx.x >> 6;
    const int img  = rest >> 1;
    const int half = rest & 1;          // which 128 pixels of the image
    const int xb   = img * 20736;
    const int pbase = half * 128;

    const int*   chT   = ch + t*CH_STRIDE;
    const int    nU    = chT[0];
    const float* tblT  = tbl + t*NNODE*64;
    const int*   metaT = meta + t*H0*8;

    // ---- phase A: layer 0; wave w owns slots [w*npw, min(..+npw, nU)) ----
    const int npw  = (nU + 3) >> 2;
    const int sBeg = w * npw;
    const int sEnd = (sBeg + npw < nU) ? sBeg + npw : nU;
    for (int s = sBeg; s < sEnd; ++s) {
        const int n = chT[1 + s];
        const int4* mp = (const int4*)(metaT + n*8);
        const int4 m0 = mp[0], m1 = mp[1];
        float4 lo4[8], dd4[8];
        load_tbl(tblT + n*64, lo4, dd4);
#pragma unroll
        for (int c = 0; c < 2; ++c) {
            const int px = (c << 6) + lane;          // 0..127 within block
            const int gp = pbase + px;               // 0..255 within image
            const int base = xb + ((gp >> 4) << 1)*36 + ((gp & 15) << 1);
            float g[NB];
            g[0] = xp[base + m0.x]; g[1] = xp[base + m0.y]; g[2] = xp[base + m0.z];
            g[3] = xp[base + m0.w]; g[4] = xp[base + m1.x]; g[5] = xp[base + m1.y];
            h0s[s*128 + px] = lut_contract_reg(lo4, dd4, g);
        }
    }
    __syncthreads();

    // ---- phase B: layer 1; 6 nodes round-robin over 4 waves ----
    for (int n = w; n < H1; n += 4) {
        float4 lo4[8], dd4[8];
        load_tbl(tblT + (H0 + n)*64, lo4, dd4);
        const int* i1 = chT + 1 + H0 + n*NB;
        const int s0 = i1[0], s1 = i1[1], s2 = i1[2];
        const int s3 = i1[3], s4 = i1[4], s5 = i1[5];
#pragma unroll
        for (int c = 0; c < 2; ++c) {
            const int px = (c << 6) + lane;
            float g[NB];
            g[0] = h0s[s0*128 + px]; g[1] = h0s[s1*128 + px]; g[2] = h0s[s2*128 + px];
            g[3] = h0s[s3*128 + px]; g[4] = h0s[s4*128 + px]; g[5] = h0s[s5*128 + px];
            h1s[n*128 + px] = lut_contract_reg(lo4, dd4, g);
        }
    }
    __syncthreads();

    // ---- phase C: layer 2; 2 chunks on waves 0,1 ----
    if (w < 2) {
        float4 lo4[8], dd4[8];
        load_tbl(tblT + (H0 + H1)*64, lo4, dd4);
        const int* i2 = idx2 + t*NB;
        const int px = (w << 6) + lane;
        float g[NB];
#pragma unroll
        for (int i = 0; i < NB; ++i) g[i] = h1s[i2[i]*128 + px];
        out[((size_t)img*COUT + t)*256 + pbase + px] = lut_contract_reg(lo4, dd4, g);
    }
}

extern "C" void kernel_launch(void* const* d_in, const int* in_sizes, int n_in,
                              void* d_out, int out_size, void* d_ws, size_t ws_size,
                              hipStream_t stream) {
    const float* x      = (const float*)d_in[0];
    const int*   idx0   = (const int*)  d_in[1];
    const float* table0 = (const float*)d_in[2];
    const int*   idx1   = (const int*)  d_in[3];
    const float* table1 = (const float*)d_in[4];
    const int*   idx2   = (const int*)  d_in[5];
    const float* table2 = (const float*)d_in[6];
    float* out = (float*)d_out;
    float* ws  = (float*)d_ws;

    const int setup_items = XPN + COUT*NNODE*32 + COUT*H0*NB + COUT;
    setup_kernel<<<(setup_items + 255)/256, 256, 0, stream>>>(
        x, table0, table1, table2, idx0, idx1, ws);

    const float* xp   = ws;
    const float* tbl  = ws + TBL_OFF;
    const int*   meta = (const int*)ws + META_OFF_I;
    const int*   ch   = (const int*)ws + CH_OFF_I;

    lutfused_kernel<<<COUT * B_IMG * 2, 256, 0, stream>>>(xp, tbl, meta, ch, idx2, out);
}

// Round 9
// 21.827 us; speedup vs baseline: 2.1549x; 1.7391x over previous
//
#include <hip/hip_runtime.h>

// Problem constants
#define B_IMG 8
#define C_IN  16
#define COUT  64
#define H0    36
#define H1    6
#define NB    6
#define NNODE 43
// OH=OW=16; output [8][64][16][16]

typedef float f32x2 __attribute__((ext_vector_type(2)));

__device__ __forceinline__ float sigf(float v) { return 1.0f / (1.0f + __expf(-v)); }

// 6-bit multilinear interp, delta-form table in registers.
// g[0] contracts the MSB ... g[5] the LSB (matches reference einsum order).
__device__ __forceinline__ float lut_contract_reg(const float4 lo4[8], const float4 dd4[8],
                                                  const float g[NB]) {
    f32x2 v[16];
    const float g0 = g[0];
#pragma unroll
    for (int q = 0; q < 8; ++q) {
        v[2*q+0] = (f32x2){lo4[q].x, lo4[q].y} + (f32x2){dd4[q].x, dd4[q].y} * g0;
        v[2*q+1] = (f32x2){lo4[q].z, lo4[q].w} + (f32x2){dd4[q].z, dd4[q].w} * g0;
    }
#pragma unroll
    for (int i = 1; i < 5; ++i) {
        const int vh = 16 >> i;
        const float gi = g[i];
#pragma unroll
        for (int r = 0; r < vh; ++r)
            v[r] += (v[r + vh] - v[r]) * gi;
    }
    return v[0].x + (v[0].y - v[0].x) * g[5];
}

// Read a 64-entry delta table from LDS (wave-uniform addr -> broadcast reads).
__device__ __forceinline__ void load_tbl_lds(const float* tb, float4 lo4[8], float4 dd4[8]) {
    const float4* t4 = (const float4*)tb;
#pragma unroll
    for (int q = 0; q < 8; ++q) { lo4[q] = t4[q]; dd4[q] = t4[q + 8]; }
}

// Single fused kernel: block = (channel t, image img), 512 threads = 8 waves,
// 256 pixels. All per-channel setup (sigmoid tables -> LDS, idx decode, prune
// mask) is done in-block: no setup kernel, no workspace, no cross-block deps.
__global__ __launch_bounds__(512, 4) void lutone_kernel(
    const float* __restrict__ x,
    const int*   __restrict__ idx0,
    const float* __restrict__ t0,
    const int*   __restrict__ idx1,
    const float* __restrict__ t1,
    const int*   __restrict__ idx2,
    const float* __restrict__ t2,
    float*       __restrict__ out)
{
    __shared__ float tblL[NNODE*64];   // sigmoid'd delta tables: lo[32]|dd[32]
    __shared__ float h0s[H0*256];      // [raw node][px] — bank = px, conflict-free
    __shared__ float h1s[H1*256];

    const int tid  = threadIdx.x;
    const int w    = tid >> 6;
    const int lane = tid & 63;
    const int t    = blockIdx.x & 63;
    const int img  = blockIdx.x >> 6;

    // ---- stage sigmoid'd delta tables into LDS (1376 pair-items) ----
    for (int e = tid; e < NNODE*32; e += 512) {
        const int node = e >> 5, k = e & 31;
        const float* src = (node < H0)      ? t0 + ((size_t)t*H0 + node)*64
                         : (node < H0+H1)   ? t1 + ((size_t)t*H1 + node - H0)*64
                                            : t2 + (size_t)t*64;
        const float lo = sigf(src[k]);
        const float hi = sigf(src[k + 32]);
        tblL[node*64 + k]      = lo;
        tblL[node*64 + 32 + k] = hi - lo;
    }

    // ---- wave-uniform metadata (scalar pipe): used-node mask ----
    const int* i1base = idx1 + t*(H1*NB);
    unsigned long long umask = 0ull;
#pragma unroll
    for (int j = 0; j < H1*NB; ++j) umask |= 1ull << i1base[j];

    // ---- per-lane pixel geometry: base addr + 25-bit (kh,kw) validity mask ----
    int base[4], vmask[4];
#pragma unroll
    for (int c = 0; c < 4; ++c) {
        const int p  = (c << 6) + lane;
        const int oh = p >> 4, ow = p & 15;
        base[c] = img*16384 + oh*64 + ow*2;            // oh2*32 + ow2
        const int hm = 0x1F ^ ((oh == 0) ? 0x03 : 0) ^ ((oh == 15) ? 0x10 : 0);
        const int wm = 0x1F ^ ((ow == 0) ? 0x03 : 0) ^ ((ow == 15) ? 0x10 : 0);
        int vm = 0;
#pragma unroll
        for (int kh = 0; kh < 5; ++kh)
            vm |= ((hm >> kh) & 1) ? (wm << (5*kh)) : 0;
        vmask[c] = vm;
    }
    __syncthreads();

    // ---- phase A: layer 0; used nodes round-robin over the 8 waves ----
    int cnt = 0;
    for (int n = 0; n < H0; ++n) {
        if (!((umask >> n) & 1ull)) continue;
        const int slot = cnt++;
        if ((slot & 7) != w) continue;

        // decode this node's 6 gather indices (uniform -> scalar regs)
        const int* i0 = idx0 + ((size_t)t*H0 + n)*NB;
        int off[NB], rem[NB];
#pragma unroll
        for (int i = 0; i < NB; ++i) {
            const int raw = i0[i];
            const int c2  = raw / 25;
            rem[i] = raw - 25*c2;                      // kh*5 + kw
            const int kh = rem[i] / 5, kw = rem[i] - 5*kh;
            off[i] = c2*1024 + kh*32 + kw - 66;        // -(2*32+2) halo shift
        }
        float4 lo4[8], dd4[8];
        load_tbl_lds(tblL + n*64, lo4, dd4);
#pragma unroll
        for (int c = 0; c < 4; ++c) {
            float g[NB];
#pragma unroll
            for (int i = 0; i < NB; ++i) {
                const bool ok = ((vmask[c] >> rem[i]) & 1) != 0;
                const float v = x[ok ? (base[c] + off[i]) : 0];
                g[i] = ok ? v : 0.0f;
            }
            h0s[n*256 + (c << 6) + lane] = lut_contract_reg(lo4, dd4, g);
        }
    }
    __syncthreads();

    // ---- phase B: layer 1; waves 0..5 own one node each (raw-id h0 reads) ----
    if (w < H1) {
        float4 lo4[8], dd4[8];
        load_tbl_lds(tblL + (H0 + w)*64, lo4, dd4);
        const int* i1 = idx1 + ((size_t)t*H1 + w)*NB;
        const int s0 = i1[0], s1 = i1[1], s2 = i1[2];
        const int s3 = i1[3], s4 = i1[4], s5 = i1[5];
#pragma unroll
        for (int c = 0; c < 4; ++c) {
            const int px = (c << 6) + lane;
            float g[NB];
            g[0] = h0s[s0*256 + px]; g[1] = h0s[s1*256 + px]; g[2] = h0s[s2*256 + px];
            g[3] = h0s[s3*256 + px]; g[4] = h0s[s4*256 + px]; g[5] = h0s[s5*256 + px];
            h1s[w*256 + px] = lut_contract_reg(lo4, dd4, g);
        }
    }
    __syncthreads();

    // ---- phase C: layer 2; waves 0..3 take one 64-px chunk each ----
    if (w < 4) {
        float4 lo4[8], dd4[8];
        load_tbl_lds(tblL + (H0 + H1)*64, lo4, dd4);
        const int* i2 = idx2 + (size_t)t*NB;
        const int px = (w << 6) + lane;
        float g[NB];
#pragma unroll
        for (int i = 0; i < NB; ++i) g[i] = h1s[i2[i]*256 + px];
        out[((size_t)img*COUT + t)*256 + px] = lut_contract_reg(lo4, dd4, g);
    }
}

extern "C" void kernel_launch(void* const* d_in, const int* in_sizes, int n_in,
                              void* d_out, int out_size, void* d_ws, size_t ws_size,
                              hipStream_t stream) {
    const float* x      = (const float*)d_in[0];
    const int*   idx0   = (const int*)  d_in[1];
    const float* table0 = (const float*)d_in[2];
    const int*   idx1   = (const int*)  d_in[3];
    const float* table1 = (const float*)d_in[4];
    const int*   idx2   = (const int*)  d_in[5];
    const float* table2 = (const float*)d_in[6];
    float* out = (float*)d_out;

    lutone_kernel<<<COUT * B_IMG, 512, 0, stream>>>(
        x, idx0, table0, idx1, table1, idx2, table2, out);
}

// Round 10
// 21.683 us; speedup vs baseline: 2.1693x; 1.0067x over previous
//
#include <hip/hip_runtime.h>

// Problem constants
#define B_IMG 8
#define C_IN  16
#define COUT  64
#define H0    36
#define H1    6
#define NB    6
#define NNODE 43
// OH=OW=16; output [8][64][16][16]

typedef float f32x2 __attribute__((ext_vector_type(2)));

__device__ __forceinline__ float sigf(float v) { return 1.0f / (1.0f + __expf(-v)); }

// 6-bit multilinear interp, delta-form table in registers.
// g[0] contracts the MSB ... g[5] the LSB (matches reference einsum order).
__device__ __forceinline__ float lut_contract_reg(const float4 lo4[8], const float4 dd4[8],
                                                  const float g[NB]) {
    f32x2 v[16];
    const float g0 = g[0];
#pragma unroll
    for (int q = 0; q < 8; ++q) {
        v[2*q+0] = (f32x2){lo4[q].x, lo4[q].y} + (f32x2){dd4[q].x, dd4[q].y} * g0;
        v[2*q+1] = (f32x2){lo4[q].z, lo4[q].w} + (f32x2){dd4[q].z, dd4[q].w} * g0;
    }
#pragma unroll
    for (int i = 1; i < 5; ++i) {
        const int vh = 16 >> i;
        const float gi = g[i];
#pragma unroll
        for (int r = 0; r < vh; ++r)
            v[r] += (v[r + vh] - v[r]) * gi;
    }
    return v[0].x + (v[0].y - v[0].x) * g[5];
}

// Read a 64-entry delta table from LDS (wave-uniform addr -> broadcast reads).
__device__ __forceinline__ void load_tbl_lds(const float* tb, float4 lo4[8], float4 dd4[8]) {
    const float4* t4 = (const float4*)tb;
#pragma unroll
    for (int q = 0; q < 8; ++q) { lo4[q] = t4[q]; dd4[q] = t4[q + 8]; }
}

// Single fused kernel: block = (channel t, image img), 512 threads = 8 waves,
// 256 pixels. Per-channel setup (sigmoid tables, idx0 decode) staged in LDS.
__global__ __launch_bounds__(512, 4) void lutone_kernel(
    const float* __restrict__ x,
    const int*   __restrict__ idx0,
    const float* __restrict__ t0,
    const int*   __restrict__ idx1,
    const float* __restrict__ t1,
    const int*   __restrict__ idx2,
    const float* __restrict__ t2,
    float*       __restrict__ out)
{
    __shared__ float tblL[NNODE*64];   // sigmoid'd delta tables: lo[32]|dd[32]
    __shared__ float h0s[H0*256];      // [raw node][px] — bank = px, conflict-free
    __shared__ float h1s[H1*256];
    __shared__ int   metaL[H0*NB*2];   // per (node,i): {off, rem}

    const int tid  = threadIdx.x;
    const int w    = tid >> 6;
    const int lane = tid & 63;
    const int t    = blockIdx.x & 63;
    const int img  = blockIdx.x >> 6;

    // ---- stage sigmoid'd delta tables into LDS ----
    for (int e = tid; e < NNODE*32; e += 512) {
        const int node = e >> 5, k = e & 31;
        const float* src = (node < H0)      ? t0 + ((size_t)t*H0 + node)*64
                         : (node < H0+H1)   ? t1 + ((size_t)t*H1 + node - H0)*64
                                            : t2 + (size_t)t*64;
        const float lo = sigf(src[k]);
        const float hi = sigf(src[k + 32]);
        tblL[node*64 + k]      = lo;
        tblL[node*64 + 32 + k] = hi - lo;
    }
    // ---- decode idx0 -> LDS meta (one thread per (node,bit)) ----
    if (tid < H0*NB) {
        const int raw = idx0[(size_t)t*(H0*NB) + tid];
        const int c2  = raw / 25;
        const int rem = raw - 25*c2;                 // kh*5 + kw
        const int kh  = rem / 5, kw = rem - 5*kh;
        metaL[tid*2 + 0] = c2*1024 + kh*32 + kw - 66;  // -(2*32+2) halo shift
        metaL[tid*2 + 1] = rem;
    }

    // ---- wave-uniform used-node mask (scalar pipe, overlaps staging) ----
    const int* i1base = idx1 + t*(H1*NB);
    unsigned long long umask = 0ull;
#pragma unroll
    for (int j = 0; j < H1*NB; ++j) umask |= 1ull << i1base[j];

    // ---- per-lane pixel geometry: base addr + 25-bit (kh,kw) validity mask ----
    int base[4], vmask[4];
#pragma unroll
    for (int c = 0; c < 4; ++c) {
        const int p  = (c << 6) + lane;
        const int oh = p >> 4, ow = p & 15;
        base[c] = img*16384 + oh*64 + ow*2;            // oh2*32 + ow2
        const int hm = 0x1F ^ ((oh == 0) ? 0x03 : 0) ^ ((oh == 15) ? 0x10 : 0);
        const int wm = 0x1F ^ ((ow == 0) ? 0x03 : 0) ^ ((ow == 15) ? 0x10 : 0);
        int vm = 0;
#pragma unroll
        for (int kh = 0; kh < 5; ++kh)
            vm |= ((hm >> kh) & 1) ? (wm << (5*kh)) : 0;
        vmask[c] = vm;
    }

    // ---- this wave's node assignment (<=5 nodes, named regs: rule #20) ----
    int myn0 = -1, myn1 = -1, myn2 = -1, myn3 = -1, myn4 = -1;
    {
        int cnt = 0;
        for (int n = 0; n < H0; ++n) {
            if (!((umask >> n) & 1ull)) continue;
            const int slot = cnt++;
            if ((slot & 7) != w) continue;
            const int k = slot >> 3;
            if      (k == 0) myn0 = n;
            else if (k == 1) myn1 = n;
            else if (k == 2) myn2 = n;
            else if (k == 3) myn3 = n;
            else             myn4 = n;
        }
    }
    __syncthreads();

    // ---- phase A: layer 0, straight-lined so the scheduler can pipeline ----
#define NODE_A(NN)                                                           \
    if ((NN) >= 0) {                                                         \
        const int4* mp = (const int4*)(metaL + (NN)*12);                     \
        const int4 ma = mp[0], mb = mp[1], mc = mp[2];                       \
        float4 lo4[8], dd4[8];                                               \
        load_tbl_lds(tblL + (NN)*64, lo4, dd4);                              \
        _Pragma("unroll")                                                    \
        for (int c = 0; c < 4; ++c) {                                        \
            const int off_[NB] = {ma.x, ma.z, mb.x, mb.z, mc.x, mc.z};       \
            const int rem_[NB] = {ma.y, ma.w, mb.y, mb.w, mc.y, mc.w};       \
            float g[NB];                                                     \
            _Pragma("unroll")                                                \
            for (int i = 0; i < NB; ++i) {                                   \
                const bool ok = ((vmask[c] >> rem_[i]) & 1) != 0;            \
                const float v = x[ok ? (base[c] + off_[i]) : 0];             \
                g[i] = ok ? v : 0.0f;                                        \
            }                                                                \
            h0s[(NN)*256 + (c << 6) + lane] = lut_contract_reg(lo4, dd4, g); \
        }                                                                    \
    }
    NODE_A(myn0)
    NODE_A(myn1)
    NODE_A(myn2)
    NODE_A(myn3)
    NODE_A(myn4)
#undef NODE_A
    __syncthreads();

    // ---- phase B: layer 1 on all 8 waves (24 chunk-units, <=3 per wave) ----
    if (w < H1) {
        // waves 0..5: own node w, chunks 0..2
        float4 lo4[8], dd4[8];
        load_tbl_lds(tblL + (H0 + w)*64, lo4, dd4);
        const int* i1 = idx1 + ((size_t)t*H1 + w)*NB;
        const int s0 = i1[0], s1 = i1[1], s2 = i1[2];
        const int s3 = i1[3], s4 = i1[4], s5 = i1[5];
#pragma unroll
        for (int c = 0; c < 3; ++c) {
            const int px = (c << 6) + lane;
            float g[NB];
            g[0] = h0s[s0*256 + px]; g[1] = h0s[s1*256 + px]; g[2] = h0s[s2*256 + px];
            g[3] = h0s[s3*256 + px]; g[4] = h0s[s4*256 + px]; g[5] = h0s[s5*256 + px];
            h1s[w*256 + px] = lut_contract_reg(lo4, dd4, g);
        }
    } else {
        // waves 6,7: chunk 3 of nodes 0..2 / 3..5
        const int nb0 = (w == 6) ? 0 : 3;
        const int px  = (3 << 6) + lane;
#pragma unroll
        for (int k = 0; k < 3; ++k) {
            const int n = nb0 + k;
            float4 lo4[8], dd4[8];
            load_tbl_lds(tblL + (H0 + n)*64, lo4, dd4);
            const int* i1 = idx1 + ((size_t)t*H1 + n)*NB;
            float g[NB];
            g[0] = h0s[i1[0]*256 + px]; g[1] = h0s[i1[1]*256 + px];
            g[2] = h0s[i1[2]*256 + px]; g[3] = h0s[i1[3]*256 + px];
            g[4] = h0s[i1[4]*256 + px]; g[5] = h0s[i1[5]*256 + px];
            h1s[n*256 + px] = lut_contract_reg(lo4, dd4, g);
        }
    }
    __syncthreads();

    // ---- phase C: layer 2; waves 0..3 take one 64-px chunk each ----
    if (w < 4) {
        float4 lo4[8], dd4[8];
        load_tbl_lds(tblL + (H0 + H1)*64, lo4, dd4);
        const int* i2 = idx2 + (size_t)t*NB;
        const int px = (w << 6) + lane;
        float g[NB];
#pragma unroll
        for (int i = 0; i < NB; ++i) g[i] = h1s[i2[i]*256 + px];
        out[((size_t)img*COUT + t)*256 + px] = lut_contract_reg(lo4, dd4, g);
    }
}

extern "C" void kernel_launch(void* const* d_in, const int* in_sizes, int n_in,
                              void* d_out, int out_size, void* d_ws, size_t ws_size,
                              hipStream_t stream) {
    const float* x      = (const float*)d_in[0];
    const int*   idx0   = (const int*)  d_in[1];
    const float* table0 = (const float*)d_in[2];
    const int*   idx1   = (const int*)  d_in[3];
    const float* table1 = (const float*)d_in[4];
    const int*   idx2   = (const int*)  d_in[5];
    const float* table2 = (const float*)d_in[6];
    float* out = (float*)d_out;

    lutone_kernel<<<COUT * B_IMG, 512, 0, stream>>>(
        x, idx0, table0, idx1, table1, idx2, table2, out);
}